// Round 10
// baseline (123.949 us; speedup 1.0000x reference)
//
#include <hip/hip_runtime.h>
#include <float.h>

#define Bb 2
#define Ll 256
#define Ss 384
#define Hh 768
#define Tc 16
#define Dc 50
#define WD 100
#define CV 128
#define NG 200     // 4*Dc gates
#define OUTC 968   // H + WD + 2*Dc

// ws layout (floats):
//   [0, 128)      minv partials
//   [128, ...)    xproj table [2][128][200], bias folded in

__device__ inline float tanh_fast(float x) {
    float e = __expf(2.f * x);
    return 1.f - 2.f / (e + 1.f);
}
__device__ inline float sigmoid_fast(float x) {
    return 1.f / (1.f + __expf(-x));
}

// ================= kernel 1: min partials | xproj =================
// grid 144: [0,128) min, [128,144) xproj

__global__ __launch_bounds__(256) void kernel1(
        const float* __restrict__ bert, const float* __restrict__ char_table,
        const float* __restrict__ Wih_f, const float* __restrict__ bih_f, const float* __restrict__ bhh_f,
        const float* __restrict__ Wih_b, const float* __restrict__ bih_b, const float* __restrict__ bhh_b,
        float* __restrict__ minp, float* __restrict__ xpt) {
    int blk = blockIdx.x, tid = threadIdx.x;
    if (blk < 128) {
        const int n4 = (Bb * Ss * Hh) / 4;       // 147456 float4
        const float4* b4 = (const float4*)bert;
        float m = FLT_MAX;
        for (int i = blk * 256 + tid; i < n4; i += 128 * 256) {
            float4 v = b4[i];
            m = fminf(m, fminf(fminf(v.x, v.y), fminf(v.z, v.w)));
        }
        #pragma unroll
        for (int off = 32; off; off >>= 1) m = fminf(m, __shfl_down(m, off, 64));
        __shared__ float red[4];
        if ((tid & 63) == 0) red[tid >> 6] = m;
        __syncthreads();
        if (tid == 0) minp[blk] = fminf(fminf(red[0], red[1]), fminf(red[2], red[3]));
    } else {
        int idx = blk - 128;            // dir*8 + cid-chunk
        int dir = idx >> 3, c0 = (idx & 7) * 16;
        const float* Wih = dir ? Wih_b : Wih_f;
        const float* bih = dir ? bih_b : bih_f;
        const float* bhh = dir ? bhh_b : bhh_f;
        __shared__ float ct[16][Dc];
        for (int e = tid; e < 16 * Dc; e += 256)
            ((float*)ct)[e] = char_table[c0 * Dc + e];
        __syncthreads();
        if (tid < NG) {
            float w[Dc];
            #pragma unroll
            for (int j = 0; j < Dc; j++) w[j] = Wih[tid * Dc + j];
            float bias = bih[tid] + bhh[tid];
            for (int cid = 0; cid < 16; cid++) {
                float a = bias;
                #pragma unroll
                for (int j = 0; j < Dc; j++) a += w[j] * ct[cid][j];
                xpt[(dir * CV + c0 + cid) * NG + tid] = a;
            }
        }
    }
}

// ================= kernel2: fused lstm | word | embed =================
// grid 1472, roles INTERLEAVED (R9 evidence: fused interleave beat the
// serial 3-kernel split by ~6.5 us):
//   blk < 1152 : blk%3==0 -> word id blk/3 (0..383),
//                else     -> lstm id (blk/3)*2 + blk%3 - 1 (0..767)
//   blk < 1408 : lstm id 768 + (blk-1152)
//   else       : embed id blk-1408
// lstm: R8-proven readlane form -- h broadcast via v_readlane (VALU pipe,
//       zero LDS traffic in phase A), redundant per-wave state update,
//       ONE barrier/step with double-buffered gsb. xg in LDS (runtime t);
//       w[50] constant-indexed full unroll.
// word: 8 rows/block, branchless additive-bias masked max. 8-row halves
//       the bert L2 re-read (151->75 MB) + p2w staging; its R8 standalone
//       failure was pure occupancy (1.75 blk/CU) which fusion removes.

__global__ __launch_bounds__(256, 4) void kernel2(
        const int* __restrict__ char_ids, const int* __restrict__ char_count,
        const float* __restrict__ Whh_f, const float* __restrict__ Whh_b,
        const float* __restrict__ xpt,
        const float* __restrict__ bert, const int* __restrict__ p2w,
        const float* __restrict__ minp,
        const int* __restrict__ word_ids, const float* __restrict__ word_table,
        float* __restrict__ out) {
    __shared__ __align__(16) char smem[28680];
    int blk = blockIdx.x, tid = threadIdx.x;

    int role, id;
    if (blk < 1152) {
        int g = blk / 3, r3 = blk - g * 3;
        role = r3 == 0 ? 0 : 1;
        id = r3 == 0 ? g : g * 2 + (r3 - 1);
    } else if (blk < 1408) { role = 1; id = 768 + (blk - 1152); }
    else { role = 2; id = blk - 1408; }

    if (role == 1) {
        // ---------------- char bi-LSTM (readlane broadcast) ----------------
        float (*xg)[NG] = (float (*)[NG])smem;            // 12800
        float (*gsb)[NG] = (float (*)[NG])(smem + 12800); // 1600
        int*   scid = (int*)(smem + 14400);               // 64

        int n = id >> 1, dir = id & 1;
        const float* Whh = dir ? Whh_b : Whh_f;
        int lane = tid & 63;

        int len = char_count[n];
        if (len < 1) len = 1;
        if (tid < Tc) {
            int st = dir ? (tid < len ? len - 1 - tid : tid) : tid;  // bwd: reverse valid prefix
            scid[tid] = char_ids[n * Tc + st];
        }
        __syncthreads();

        // stage xproj rows as float4 (row stride 200 floats = 800B, 16B aligned)
        for (int e = tid; e < Tc * (NG / 4); e += 256) {
            int t = e / 50, q = e - t * 50;
            ((float4*)xg[t])[q] = ((const float4*)&xpt[(dir * CV + scid[t]) * NG])[q];
        }
        // recurrent weight row -> regs, defined for ALL lanes (clamped row),
        // constant indices only (fully unrolled) => register-resident
        int wrow = tid < NG ? tid : NG - 1;
        bool istanh = (tid >= 100 && tid < 150);          // cell-gate rows
        float w[50];
        #pragma unroll
        for (int j = 0; j < 50; j++) w[j] = Whh[wrow * 50 + j];
        __syncthreads();

        int ch = lane < 50 ? lane : 49;                   // state channel this lane tracks
        float c = 0.f, h = 0.f, maxv = -FLT_MAX;
        for (int t = 0; t < Tc; t++) {
            // ---- A: gate pre-activation, h broadcast from own wave's lanes ----
            int hb = __float_as_int(h);
            float g0 = xg[t][wrow], g1 = 0.f, g2 = 0.f, g3 = 0.f;
            #pragma unroll
            for (int j = 0; j < 48; j += 4) {
                g0 = fmaf(__int_as_float(__builtin_amdgcn_readlane(hb, j)),     w[j],     g0);
                g1 = fmaf(__int_as_float(__builtin_amdgcn_readlane(hb, j + 1)), w[j + 1], g1);
                g2 = fmaf(__int_as_float(__builtin_amdgcn_readlane(hb, j + 2)), w[j + 2], g2);
                g3 = fmaf(__int_as_float(__builtin_amdgcn_readlane(hb, j + 3)), w[j + 3], g3);
            }
            g0 = fmaf(__int_as_float(__builtin_amdgcn_readlane(hb, 48)), w[48], g0);
            g1 = fmaf(__int_as_float(__builtin_amdgcn_readlane(hb, 49)), w[49], g1);
            float g = (g0 + g1) + (g2 + g3);
            if (tid < NG)
                gsb[t & 1][tid] = istanh ? tanh_fast(g) : sigmoid_fast(g);
            __syncthreads();                               // only barrier per step
            // ---- B: state update, redundant in every wave (h stays lane-local).
            // Race-free: A(t+2)'s write to gsb[t&1] is after barrier(t+1),
            // which every wave reaches only after its B(t) reads.
            float si = gsb[t & 1][ch];
            float sf = gsb[t & 1][ch + 50];
            float tg = gsb[t & 1][ch + 100];
            float so = gsb[t & 1][ch + 150];
            c = sf * c + si * tg;
            h = so * tanh_fast(c);
            if (t < len) maxv = fmaxf(maxv, h);            // ragged max
        }
        if (tid < 50)
            out[(size_t)n * OUTC + (Hh + WD) + dir * Dc + tid] = maxv;
    } else if (role == 0) {
        // ---------------- word_reps masked max, branchless, 8 rows ----------------
        float (*sm)[8] = (float (*)[8])smem;                       // 12288
        float (*sacc)[8][128] = (float (*)[8][128])(smem + 12288); // 16384
        float* sminv = (float*)(smem + 28672);

        int hc  = id % 6;              // h-chunk of 128
        int lt  = (id / 6) & 31;       // l-tile of 8
        int b   = id / 192;
        int l0  = lt * 8;

        // stage mask bias, coalesced global reads (s-fast within a row)
        const int* pm = p2w + ((size_t)(b * Ll + l0)) * Ss;
        for (int e = tid; e < 8 * Ss; e += 256) {
            int r = e / Ss, s = e - r * Ss;
            sm[s][r] = pm[r * Ss + s] ? 0.f : -FLT_MAX;
        }
        if (tid < 64) {
            float m = fminf(minp[tid], minp[tid + 64]);
            #pragma unroll
            for (int off = 32; off; off >>= 1) m = fminf(m, __shfl_down(m, off, 64));
            if (tid == 0) *sminv = m;
        }
        __syncthreads();

        int w    = tid >> 6;           // wave -> s range [w*96, w*96+96)
        int lane = tid & 63;
        int s0 = w * 96;

        const float2* bb2 = (const float2*)(bert + (size_t)b * Ss * Hh) + hc * 64 + lane;
        float2 acc[8];
        #pragma unroll
        for (int r = 0; r < 8; r++) { acc[r].x = -FLT_MAX; acc[r].y = -FLT_MAX; }

        for (int jo = 0; jo < 96; jo += 8) {       // 8 loads in flight per group
            float2 v[8];
            #pragma unroll
            for (int k = 0; k < 8; k++) v[k] = bb2[(size_t)(s0 + jo + k) * 384];
            #pragma unroll
            for (int k = 0; k < 8; k++) {
                int j = s0 + jo + k;
                float4 q0 = *(const float4*)&sm[j][0];   // broadcast, rows 0..3
                float4 q1 = *(const float4*)&sm[j][4];   // broadcast, rows 4..7
                acc[0].x = fmaxf(acc[0].x, v[k].x + q0.x);
                acc[0].y = fmaxf(acc[0].y, v[k].y + q0.x);
                acc[1].x = fmaxf(acc[1].x, v[k].x + q0.y);
                acc[1].y = fmaxf(acc[1].y, v[k].y + q0.y);
                acc[2].x = fmaxf(acc[2].x, v[k].x + q0.z);
                acc[2].y = fmaxf(acc[2].y, v[k].y + q0.z);
                acc[3].x = fmaxf(acc[3].x, v[k].x + q0.w);
                acc[3].y = fmaxf(acc[3].y, v[k].y + q0.w);
                acc[4].x = fmaxf(acc[4].x, v[k].x + q1.x);
                acc[4].y = fmaxf(acc[4].y, v[k].y + q1.x);
                acc[5].x = fmaxf(acc[5].x, v[k].x + q1.y);
                acc[5].y = fmaxf(acc[5].y, v[k].y + q1.y);
                acc[6].x = fmaxf(acc[6].x, v[k].x + q1.z);
                acc[6].y = fmaxf(acc[6].y, v[k].y + q1.z);
                acc[7].x = fmaxf(acc[7].x, v[k].x + q1.w);
                acc[7].y = fmaxf(acc[7].y, v[k].y + q1.w);
            }
        }
        #pragma unroll
        for (int r = 0; r < 8; r++)
            *(float2*)&sacc[w][r][lane * 2] = acc[r];
        __syncthreads();

        float mv = *sminv;
        for (int e = tid; e < 8 * 128; e += 256) {
            int r = e >> 7, cx = e & 127;
            float m = fmaxf(fmaxf(sacc[0][r][cx], sacc[1][r][cx]),
                            fmaxf(sacc[2][r][cx], sacc[3][r][cx]));
            if (m == -FLT_MAX) m = mv;             // fully-masked row -> global min fill
            out[((size_t)(b * Ll + l0 + r)) * OUTC + hc * 128 + cx] = m;
        }
    } else {
        // ---------------- word embedding gather ----------------
        for (int i = id * 256 + tid; i < Bb * Ll * WD; i += 64 * 256) {
            int bl = i / WD, d = i - bl * WD;
            out[(size_t)bl * OUTC + Hh + d] = word_table[(size_t)word_ids[bl] * WD + d];
        }
    }
}

extern "C" void kernel_launch(void* const* d_in, const int* in_sizes, int n_in,
                              void* d_out, int out_size, void* d_ws, size_t ws_size,
                              hipStream_t stream) {
    const float* bert       = (const float*)d_in[0];
    const int*   p2w        = (const int*)d_in[1];
    const int*   word_ids   = (const int*)d_in[2];
    const int*   char_count = (const int*)d_in[3];
    const int*   char_ids   = (const int*)d_in[4];
    // d_in[5] token_masks_char: consistent with char_count, unused
    const float* word_table = (const float*)d_in[6];
    const float* char_table = (const float*)d_in[7];
    const float* Wih_f = (const float*)d_in[8];
    const float* Whh_f = (const float*)d_in[9];
    const float* bih_f = (const float*)d_in[10];
    const float* bhh_f = (const float*)d_in[11];
    const float* Wih_b = (const float*)d_in[12];
    const float* Whh_b = (const float*)d_in[13];
    const float* bih_b = (const float*)d_in[14];
    const float* bhh_b = (const float*)d_in[15];
    float* out = (float*)d_out;

    float* minp = (float*)d_ws;          // 128 floats
    float* xpt  = minp + 128;            // 2*128*200 floats

    kernel1<<<144, 256, 0, stream>>>(
        bert, char_table, Wih_f, bih_f, bhh_f, Wih_b, bih_b, bhh_b,
        minp, xpt);
    kernel2<<<1472, 256, 0, stream>>>(
        char_ids, char_count, Whh_f, Whh_b, xpt, bert, p2w, minp,
        word_ids, word_table, out);
}